// Round 4
// baseline (1078.305 us; speedup 1.0000x reference)
//
#include <hip/hip_runtime.h>
#include <hip/hip_bf16.h>

#define N_NODES 100000
#define N_EDGES 1250000
#define HID 64

typedef float f32x4 __attribute__((ext_vector_type(4)));

__device__ __forceinline__ float bf2f(ushort u) {
    union { unsigned int i; float f; } v; v.i = ((unsigned int)u) << 16; return v.f;
}
__device__ __forceinline__ ushort f2bf(float f) {
    union { float f; unsigned int i; } v; v.f = f;
    unsigned int x = v.i;
    return (ushort)((x + 0x7fffu + ((x >> 16) & 1u)) >> 16);  // RNE
}

__global__ __launch_bounds__(256) void zero_kernel(float4* __restrict__ p, int n4) {
    int i = blockIdx.x * 256 + threadIdx.x;
    if (i < n4) p[i] = make_float4(0.f, 0.f, 0.f, 0.f);
}

// h0[i][:] = bf16(emb[x[i]][:])  — emb f32, h0 bf16. 4 f32 per thread.
__global__ __launch_bounds__(256) void embed_gather(const int* __restrict__ x,
                                                    const float* __restrict__ emb,
                                                    ushort* __restrict__ h0) {
    int t = blockIdx.x * 256 + threadIdx.x;
    if (t >= N_NODES * 16) return;
    int row = t >> 4, c = t & 15;
    int idx = x[row];
    float4 v = ((const float4*)(emb + (size_t)idx * HID))[c];
    ushort4 w;
    w.x = f2bf(v.x); w.y = f2bf(v.y); w.z = f2bf(v.z); w.w = f2bf(v.w);
    ((ushort4*)(h0 + (size_t)row * HID))[c] = w;
}

__global__ __launch_bounds__(256) void degree_kernel(const int* __restrict__ dst,
                                                     int* __restrict__ cnt) {
    int e = blockIdx.x * 256 + threadIdx.x;
    if (e < N_EDGES) atomicAdd(&cnt[dst[e]], 1);  // int atomic: always safe
}

// Single-block exclusive scan of cnt[0..N) -> rowptr, cur. rowptr[N] = E.
__global__ __launch_bounds__(1024) void scan_kernel(const int* __restrict__ cnt,
                                                    int* __restrict__ rowptr,
                                                    int* __restrict__ cur) {
    __shared__ int wsum[16];
    __shared__ int carry_s;
    const int tid = threadIdx.x;
    const int lane = tid & 63, wave = tid >> 6;
    if (tid == 0) carry_s = 0;
    __syncthreads();
    for (int base = 0; base < N_NODES; base += 1024) {
        int i = base + tid;
        int v = (i < N_NODES) ? cnt[i] : 0;
        int x = v;
#pragma unroll
        for (int d = 1; d < 64; d <<= 1) {
            int y = __shfl_up(x, d, 64);
            if (lane >= d) x += y;
        }
        if (lane == 63) wsum[wave] = x;
        __syncthreads();
        int carry = carry_s;
        if (wave == 0) {
            int s = (lane < 16) ? wsum[lane] : 0;
#pragma unroll
            for (int d = 1; d < 16; d <<= 1) {
                int y = __shfl_up(s, d, 64);
                if (lane >= d) s += y;
            }
            if (lane < 16) wsum[lane] = s;  // inclusive wave sums
        }
        __syncthreads();
        int waveoff = (wave == 0) ? 0 : wsum[wave - 1];
        int excl = carry + waveoff + (x - v);
        if (i < N_NODES) { rowptr[i] = excl; cur[i] = excl; }
        __syncthreads();
        if (tid == 0) carry_s += wsum[15];
        __syncthreads();
    }
    if (tid == 0) rowptr[N_NODES] = N_EDGES;
}

__global__ __launch_bounds__(256) void fill_kernel(const int* __restrict__ src,
                                                   const int* __restrict__ dst,
                                                   int* __restrict__ cur,
                                                   int* __restrict__ csr_src) {
    int e = blockIdx.x * 256 + threadIdx.x;
    if (e >= N_EDGES) return;
    int d = dst[e];
    int pos = atomicAdd(&cur[d], 1);  // int atomic: safe
    csr_src[pos] = src[e];
}

// mean[node][lane] = (1/deg) * sum_{s in N(node)} h[s][lane]; 0 if deg==0.
// One wave per node, lane = dim.
__global__ __launch_bounds__(256) void agg_mean(const int* __restrict__ rowptr,
                                                const int* __restrict__ csr_src,
                                                const ushort* __restrict__ h,
                                                ushort* __restrict__ mean) {
    int node = blockIdx.x * 4 + (threadIdx.x >> 6);
    int lane = threadIdx.x & 63;
    if (node >= N_NODES) return;
    int beg = rowptr[node], end = rowptr[node + 1];
    float acc = 0.f;
    for (int i = beg; i < end; ++i) {
        int s = csr_src[i];
        acc += bf2f(h[(size_t)s * HID + lane]);
    }
    float m = (end > beg) ? acc * (1.0f / (float)(end - beg)) : 0.f;
    mean[(size_t)node * HID + lane] = f2bf(m);
}

// out = [HAS_MEAN: mean@Wl +] bl + hin@Wr, optional PReLU.
// VALU outer-product GEMM: 64 rows/block, 16x16 thread grid, 4x4 f32 acc.
// OUT_F32: store float32 (final output), else bf16 (intermediates).
template <bool HAS_MEAN, bool HAS_PRELU, bool OUT_F32>
__global__ __launch_bounds__(256) void gemm_valu(const ushort* __restrict__ mean,
                                                 const ushort* __restrict__ hin,
                                                 const float* __restrict__ Wl,
                                                 const float* __restrict__ bl,
                                                 const float* __restrict__ Wr,
                                                 const float* __restrict__ alpha_p,
                                                 void* __restrict__ out_p, int n) {
    __shared__ float sMt[HAS_MEAN ? 64 : 1][68];  // [k][r] transposed
    __shared__ float sHt[64][68];                 // [k][r] transposed
    __shared__ float sWl[HAS_MEAN ? 64 : 1][68];  // [k][n] natural
    __shared__ float sWr[64][68];                 // [k][n] natural

    const int tid = threadIdx.x;
    const int row0 = blockIdx.x * 64;

    for (int idx = tid; idx < HID * HID; idx += 256) {
        int k = idx >> 6, nn = idx & 63;
        if (HAS_MEAN) sWl[k][nn] = Wl[idx];   // W[k][n], coalesced
        sWr[k][nn] = Wr[idx];
        int r = k, d = nn;                    // reuse decomposition: coalesced h read
        int g = row0 + r;
        float hv = 0.f, mv = 0.f;
        if (g < n) {
            hv = bf2f(hin[(size_t)g * HID + d]);
            if (HAS_MEAN) mv = bf2f(mean[(size_t)g * HID + d]);
        }
        sHt[d][r] = hv;                       // transposed store
        if (HAS_MEAN) sMt[d][r] = mv;
    }
    __syncthreads();

    const int i = tid & 15, j = tid >> 4;     // row group, col group
    const int r0 = i * 4, c0 = j * 4;
    float acc[4][4] = {};

    for (int k = 0; k < HID; ++k) {
        f32x4 hr = *(const f32x4*)&sHt[k][r0];
        f32x4 wr = *(const f32x4*)&sWr[k][c0];
#pragma unroll
        for (int a = 0; a < 4; ++a)
#pragma unroll
            for (int b = 0; b < 4; ++b)
                acc[a][b] += hr[a] * wr[b];
        if (HAS_MEAN) {
            f32x4 mr = *(const f32x4*)&sMt[k][r0];
            f32x4 wl = *(const f32x4*)&sWl[k][c0];
#pragma unroll
            for (int a = 0; a < 4; ++a)
#pragma unroll
                for (int b = 0; b < 4; ++b)
                    acc[a][b] += mr[a] * wl[b];
        }
    }

    const float alpha = HAS_PRELU ? alpha_p[0] : 0.f;
    const float b0 = bl[c0], b1 = bl[c0 + 1], b2 = bl[c0 + 2], b3 = bl[c0 + 3];
#pragma unroll
    for (int a = 0; a < 4; ++a) {
        int g = row0 + r0 + a;
        if (g < n) {
            float v0 = acc[a][0] + b0, v1 = acc[a][1] + b1;
            float v2 = acc[a][2] + b2, v3 = acc[a][3] + b3;
            if (HAS_PRELU) {
                v0 = (v0 >= 0.f) ? v0 : alpha * v0;
                v1 = (v1 >= 0.f) ? v1 : alpha * v1;
                v2 = (v2 >= 0.f) ? v2 : alpha * v2;
                v3 = (v3 >= 0.f) ? v3 : alpha * v3;
            }
            if (OUT_F32) {
                float4 w = make_float4(v0, v1, v2, v3);
                *(float4*)&((float*)out_p)[(size_t)g * HID + c0] = w;
            } else {
                ushort4 w;
                w.x = f2bf(v0); w.y = f2bf(v1); w.z = f2bf(v2); w.w = f2bf(v3);
                *(ushort4*)&((ushort*)out_p)[(size_t)g * HID + c0] = w;
            }
        }
    }
}

extern "C" void kernel_launch(void* const* d_in, const int* in_sizes, int n_in,
                              void* d_out, int out_size, void* d_ws, size_t ws_size,
                              hipStream_t stream) {
    const int*   x    = (const int*)d_in[0];
    const int*   src  = (const int*)d_in[1];
    const int*   dst  = src + N_EDGES;
    // d_in[2] = edge_weight: unused by reference
    const float* emb  = (const float*)d_in[3];
    const float* Wl1  = (const float*)d_in[4];
    const float* bl1  = (const float*)d_in[5];
    const float* Wr1  = (const float*)d_in[6];
    const float* a1   = (const float*)d_in[7];
    const float* Wl2  = (const float*)d_in[8];
    const float* bl2  = (const float*)d_in[9];
    const float* Wr2  = (const float*)d_in[10];
    const float* a2   = (const float*)d_in[11];
    const float* Wout = (const float*)d_in[12];
    const float* bout = (const float*)d_in[13];

    char* ws = (char*)d_ws;
    int*    cnt     = (int*)ws;                      //        0 ..   400,000
    int*    rowptr  = (int*)(ws + 400000);           //  400,000 ..   804,032
    int*    cur     = (int*)(ws + 804032);           //  804,032 .. 1,204,032
    int*    csr_src = (int*)(ws + 1204032);          // 1,204,032 .. 6,204,032
    ushort* h0      = (ushort*)(ws + 6204032);       // 12.8 MB
    ushort* h1      = (ushort*)(ws + 19004032);      // 12.8 MB
    ushort* meanb   = (ushort*)(ws + 31804032);      // 12.8 MB (end: 44.6 MB)
    ushort* h2      = h0;                            // h0 dead after layer-1 gemm

    const int gemm_blocks = (N_NODES + 63) / 64;     // 1563
    const int agg_blocks  = (N_NODES + 3) / 4;       // 25000

    zero_kernel<<<(100000 + 1023) / 1024, 256, 0, stream>>>((float4*)cnt, 100000 / 4);
    embed_gather<<<(N_NODES * 16 + 255) / 256, 256, 0, stream>>>(x, emb, h0);
    degree_kernel<<<(N_EDGES + 255) / 256, 256, 0, stream>>>(dst, cnt);
    scan_kernel<<<1, 1024, 0, stream>>>(cnt, rowptr, cur);
    fill_kernel<<<(N_EDGES + 255) / 256, 256, 0, stream>>>(src, dst, cur, csr_src);

    // layer 1
    agg_mean<<<agg_blocks, 256, 0, stream>>>(rowptr, csr_src, h0, meanb);
    gemm_valu<true, true, false><<<gemm_blocks, 256, 0, stream>>>(meanb, h0, Wl1, bl1, Wr1, a1, h1, N_NODES);

    // layer 2
    agg_mean<<<agg_blocks, 256, 0, stream>>>(rowptr, csr_src, h1, meanb);
    gemm_valu<true, true, false><<<gemm_blocks, 256, 0, stream>>>(meanb, h1, Wl2, bl2, Wr2, a2, h2, N_NODES);

    // output projection: float32 output
    gemm_valu<false, false, true><<<gemm_blocks, 256, 0, stream>>>(meanb, h2, Wout, bout, Wout, a1, d_out, N_NODES);
}

// Round 5
// 627.793 us; speedup vs baseline: 1.7176x; 1.7176x over previous
//
#include <hip/hip_runtime.h>
#include <hip/hip_bf16.h>

#define N_NODES 100000
#define N_EDGES 1250000
#define HID 64
#define LDSS 72   // LDS row stride in bf16 elems: 64 + 8 pad (144 B rows)

typedef __bf16 bf16x8 __attribute__((ext_vector_type(8)));
typedef float  f32x4  __attribute__((ext_vector_type(4)));

__device__ __forceinline__ float bf2f(ushort u) {
    union { unsigned int i; float f; } v; v.i = ((unsigned int)u) << 16; return v.f;
}
__device__ __forceinline__ ushort f2bf(float f) {
    union { float f; unsigned int i; } v; v.f = f;
    unsigned int x = v.i;
    return (ushort)((x + 0x7fffu + ((x >> 16) & 1u)) >> 16);  // RNE
}

__global__ __launch_bounds__(256) void zero_kernel(float4* __restrict__ p, int n4) {
    int i = blockIdx.x * 256 + threadIdx.x;
    if (i < n4) p[i] = make_float4(0.f, 0.f, 0.f, 0.f);
}

// h0[i][:] = bf16(emb[x[i]][:])  — emb f32, h0 bf16. 4 f32 per thread.
__global__ __launch_bounds__(256) void embed_gather(const int* __restrict__ x,
                                                    const float* __restrict__ emb,
                                                    ushort* __restrict__ h0) {
    int t = blockIdx.x * 256 + threadIdx.x;
    if (t >= N_NODES * 16) return;
    int row = t >> 4, c = t & 15;
    int idx = x[row];
    float4 v = ((const float4*)(emb + (size_t)idx * HID))[c];
    ushort4 w;
    w.x = f2bf(v.x); w.y = f2bf(v.y); w.z = f2bf(v.z); w.w = f2bf(v.w);
    ((ushort4*)(h0 + (size_t)row * HID))[c] = w;
}

__global__ __launch_bounds__(256) void degree_kernel(const int* __restrict__ dst,
                                                     int* __restrict__ cnt) {
    int e = blockIdx.x * 256 + threadIdx.x;
    if (e < N_EDGES) atomicAdd(&cnt[dst[e]], 1);  // int atomic: always safe
}

// Single-block exclusive scan of cnt[0..N) -> rowptr, cur. rowptr[N] = E.
__global__ __launch_bounds__(1024) void scan_kernel(const int* __restrict__ cnt,
                                                    int* __restrict__ rowptr,
                                                    int* __restrict__ cur) {
    __shared__ int wsum[16];
    __shared__ int carry_s;
    const int tid = threadIdx.x;
    const int lane = tid & 63, wave = tid >> 6;
    if (tid == 0) carry_s = 0;
    __syncthreads();
    for (int base = 0; base < N_NODES; base += 1024) {
        int i = base + tid;
        int v = (i < N_NODES) ? cnt[i] : 0;
        int x = v;
#pragma unroll
        for (int d = 1; d < 64; d <<= 1) {
            int y = __shfl_up(x, d, 64);
            if (lane >= d) x += y;
        }
        if (lane == 63) wsum[wave] = x;
        __syncthreads();
        int carry = carry_s;
        if (wave == 0) {
            int s = (lane < 16) ? wsum[lane] : 0;
#pragma unroll
            for (int d = 1; d < 16; d <<= 1) {
                int y = __shfl_up(s, d, 64);
                if (lane >= d) s += y;
            }
            if (lane < 16) wsum[lane] = s;  // inclusive wave sums
        }
        __syncthreads();
        int waveoff = (wave == 0) ? 0 : wsum[wave - 1];
        int excl = carry + waveoff + (x - v);
        if (i < N_NODES) { rowptr[i] = excl; cur[i] = excl; }
        __syncthreads();
        if (tid == 0) carry_s += wsum[15];
        __syncthreads();
    }
    if (tid == 0) rowptr[N_NODES] = N_EDGES;
}

__global__ __launch_bounds__(256) void fill_kernel(const int* __restrict__ src,
                                                   const int* __restrict__ dst,
                                                   int* __restrict__ cur,
                                                   int* __restrict__ csr_src) {
    int e = blockIdx.x * 256 + threadIdx.x;
    if (e >= N_EDGES) return;
    int d = dst[e];
    int pos = atomicAdd(&cur[d], 1);  // int atomic: safe
    csr_src[pos] = src[e];
}

// mean[node][lane] = (1/deg) * sum_{s in N(node)} h[s][lane]; 0 if deg==0.
// One wave per node, lane = dim.
__global__ __launch_bounds__(256) void agg_mean(const int* __restrict__ rowptr,
                                                const int* __restrict__ csr_src,
                                                const ushort* __restrict__ h,
                                                ushort* __restrict__ mean) {
    int node = blockIdx.x * 4 + (threadIdx.x >> 6);
    int lane = threadIdx.x & 63;
    if (node >= N_NODES) return;
    int beg = rowptr[node], end = rowptr[node + 1];
    float acc = 0.f;
    for (int i = beg; i < end; ++i) {
        int s = csr_src[i];
        acc += bf2f(h[(size_t)s * HID + lane]);
    }
    float m = (end > beg) ? acc * (1.0f / (float)(end - beg)) : 0.f;
    mean[(size_t)node * HID + lane] = f2bf(m);
}

// out = [HAS_MEAN: mean@Wl +] bl + hin@Wr, optional PReLU.
// MFMA 16x16x32 bf16: 64 rows/block, 4 waves; wave w computes rows w*16..w*16+15.
// Tiny register footprint (one f32x4 acc live per nt tile) — no spill.
template <bool HAS_MEAN, bool HAS_PRELU, bool OUT_F32>
__global__ __launch_bounds__(256) void gemm_mfma(const ushort* __restrict__ mean,
                                                 const ushort* __restrict__ hin,
                                                 const float* __restrict__ Wl,
                                                 const float* __restrict__ bl,
                                                 const float* __restrict__ Wr,
                                                 const float* __restrict__ alpha_p,
                                                 void* __restrict__ out_p, int n) {
    __shared__ __align__(16) ushort sA[HAS_MEAN ? 64 : 1][LDSS];   // mean rows, bf16
    __shared__ __align__(16) ushort sH[64][LDSS];                  // h rows, bf16
    __shared__ __align__(16) ushort sWl[HAS_MEAN ? 64 : 1][LDSS];  // Wl^T: [n][k]
    __shared__ __align__(16) ushort sWr[64][LDSS];                 // Wr^T: [n][k]

    const int tid = threadIdx.x;
    const int row0 = blockIdx.x * 64;

    // stage weights transposed + f32->bf16: sW[n][k] = bf16(W[k*64+n]) (coalesced read)
    for (int idx = tid; idx < HID * HID; idx += 256) {
        int k = idx >> 6, nn = idx & 63;
        if (HAS_MEAN) sWl[nn][k] = f2bf(Wl[idx]);
        sWr[nn][k] = f2bf(Wr[idx]);
    }
    // stage h / mean rows (bf16, coalesced 2B-per-lane)
    for (int idx = tid; idx < 64 * HID; idx += 256) {
        int r = idx >> 6, d = idx & 63;
        int g = row0 + r;
        ushort hv = 0, av = 0;
        if (g < n) {
            hv = hin[(size_t)g * HID + d];
            if (HAS_MEAN) av = mean[(size_t)g * HID + d];
        }
        sH[r][d] = hv;
        if (HAS_MEAN) sA[r][d] = av;
    }
    __syncthreads();

    const int wave = tid >> 6;
    const int lane = tid & 63;
    const int quad = lane >> 4;   // k-group: lanes hold k = quad*8 .. quad*8+7
    const int lr = lane & 15;
    const int r0 = wave * 16;

    const float alpha = HAS_PRELU ? alpha_p[0] : 0.f;

    for (int nt = 0; nt < 4; ++nt) {
        f32x4 acc = {0.f, 0.f, 0.f, 0.f};
#pragma unroll
        for (int ks = 0; ks < 2; ++ks) {
            int k0 = ks * 32 + quad * 8;
            bf16x8 hf = *(const bf16x8*)&sH[r0 + lr][k0];
            bf16x8 wr = *(const bf16x8*)&sWr[nt * 16 + lr][k0];
            acc = __builtin_amdgcn_mfma_f32_16x16x32_bf16(hf, wr, acc, 0, 0, 0);
            if (HAS_MEAN) {
                bf16x8 af = *(const bf16x8*)&sA[r0 + lr][k0];
                bf16x8 wl = *(const bf16x8*)&sWl[nt * 16 + lr][k0];
                acc = __builtin_amdgcn_mfma_f32_16x16x32_bf16(af, wl, acc, 0, 0, 0);
            }
        }
        int col = nt * 16 + lr;
        float bias = bl[col];
#pragma unroll
        for (int r = 0; r < 4; ++r) {
            int row = r0 + quad * 4 + r;  // C/D layout: col=lane&15, row=(lane>>4)*4+reg [m89]
            int g = row0 + row;
            if (g < n) {
                float v = acc[r] + bias;
                if (HAS_PRELU) v = (v >= 0.f) ? v : alpha * v;
                if (OUT_F32)
                    ((float*)out_p)[(size_t)g * HID + col] = v;
                else
                    ((ushort*)out_p)[(size_t)g * HID + col] = f2bf(v);
            }
        }
    }
}

extern "C" void kernel_launch(void* const* d_in, const int* in_sizes, int n_in,
                              void* d_out, int out_size, void* d_ws, size_t ws_size,
                              hipStream_t stream) {
    const int*   x    = (const int*)d_in[0];
    const int*   src  = (const int*)d_in[1];
    const int*   dst  = src + N_EDGES;
    // d_in[2] = edge_weight: unused by reference
    const float* emb  = (const float*)d_in[3];
    const float* Wl1  = (const float*)d_in[4];
    const float* bl1  = (const float*)d_in[5];
    const float* Wr1  = (const float*)d_in[6];
    const float* a1   = (const float*)d_in[7];
    const float* Wl2  = (const float*)d_in[8];
    const float* bl2  = (const float*)d_in[9];
    const float* Wr2  = (const float*)d_in[10];
    const float* a2   = (const float*)d_in[11];
    const float* Wout = (const float*)d_in[12];
    const float* bout = (const float*)d_in[13];

    char* ws = (char*)d_ws;
    int*    cnt     = (int*)ws;                      //        0 ..   400,000
    int*    rowptr  = (int*)(ws + 400000);           //  400,000 ..   804,032
    int*    cur     = (int*)(ws + 804032);           //  804,032 .. 1,204,032
    int*    csr_src = (int*)(ws + 1204032);          // 1,204,032 .. 6,204,032
    ushort* h0      = (ushort*)(ws + 6204032);       // 12.8 MB
    ushort* h1      = (ushort*)(ws + 19004032);      // 12.8 MB
    ushort* meanb   = (ushort*)(ws + 31804032);      // 12.8 MB (end: 44.6 MB)
    ushort* h2      = h0;                            // h0 dead after layer-1 gemm

    const int gemm_blocks = (N_NODES + 63) / 64;     // 1563
    const int agg_blocks  = (N_NODES + 3) / 4;       // 25000

    zero_kernel<<<(100000 + 1023) / 1024, 256, 0, stream>>>((float4*)cnt, 100000 / 4);
    embed_gather<<<(N_NODES * 16 + 255) / 256, 256, 0, stream>>>(x, emb, h0);
    degree_kernel<<<(N_EDGES + 255) / 256, 256, 0, stream>>>(dst, cnt);
    scan_kernel<<<1, 1024, 0, stream>>>(cnt, rowptr, cur);
    fill_kernel<<<(N_EDGES + 255) / 256, 256, 0, stream>>>(src, dst, cur, csr_src);

    // layer 1
    agg_mean<<<agg_blocks, 256, 0, stream>>>(rowptr, csr_src, h0, meanb);
    gemm_mfma<true, true, false><<<gemm_blocks, 256, 0, stream>>>(meanb, h0, Wl1, bl1, Wr1, a1, h1, N_NODES);

    // layer 2
    agg_mean<<<agg_blocks, 256, 0, stream>>>(rowptr, csr_src, h1, meanb);
    gemm_mfma<true, true, false><<<gemm_blocks, 256, 0, stream>>>(meanb, h1, Wl2, bl2, Wr2, a2, h2, N_NODES);

    // output projection: float32 output
    gemm_mfma<false, false, true><<<gemm_blocks, 256, 0, stream>>>(meanb, h2, Wout, bout, Wout, a1, d_out, N_NODES);
}

// Round 6
// 406.403 us; speedup vs baseline: 2.6533x; 1.5448x over previous
//
#include <hip/hip_runtime.h>
#include <hip/hip_bf16.h>

#define N_NODES 100000
#define N_EDGES 1250000
#define HID 64
#define LDSS 72   // LDS row stride in bf16 elems: 64 + 8 pad (144 B rows)
#define SCAN_TILE 1024
#define NBLK ((N_NODES + SCAN_TILE - 1) / SCAN_TILE)   // 98

typedef __bf16 bf16x8 __attribute__((ext_vector_type(8)));
typedef float  f32x4  __attribute__((ext_vector_type(4)));

__device__ __forceinline__ float bf2f(ushort u) {
    union { unsigned int i; float f; } v; v.i = ((unsigned int)u) << 16; return v.f;
}
__device__ __forceinline__ ushort f2bf(float f) {
    union { float f; unsigned int i; } v; v.f = f;
    unsigned int x = v.i;
    return (ushort)((x + 0x7fffu + ((x >> 16) & 1u)) >> 16);  // RNE
}

__global__ __launch_bounds__(256) void zero_kernel(float4* __restrict__ p, int n4) {
    int i = blockIdx.x * 256 + threadIdx.x;
    if (i < n4) p[i] = make_float4(0.f, 0.f, 0.f, 0.f);
}

// h0[i][:] = bf16(emb[x[i]][:])  — emb f32, h0 bf16. 4 f32 per thread.
__global__ __launch_bounds__(256) void embed_gather(const int* __restrict__ x,
                                                    const float* __restrict__ emb,
                                                    ushort* __restrict__ h0) {
    int t = blockIdx.x * 256 + threadIdx.x;
    if (t >= N_NODES * 16) return;
    int row = t >> 4, c = t & 15;
    int idx = x[row];
    float4 v = ((const float4*)(emb + (size_t)idx * HID))[c];
    ushort4 w;
    w.x = f2bf(v.x); w.y = f2bf(v.y); w.z = f2bf(v.z); w.w = f2bf(v.w);
    ((ushort4*)(h0 + (size_t)row * HID))[c] = w;
}

__global__ __launch_bounds__(256) void degree_kernel(const int* __restrict__ dst,
                                                     int* __restrict__ cnt) {
    int e = blockIdx.x * 256 + threadIdx.x;
    if (e < N_EDGES) atomicAdd(&cnt[dst[e]], 1);  // int atomic: always safe
}

// ---- parallel scan: 3 kernels, no cross-block deps ----
__global__ __launch_bounds__(SCAN_TILE) void scan_blocksum(const int* __restrict__ cnt,
                                                           int* __restrict__ bsum) {
    __shared__ int wsum[16];
    const int tid = threadIdx.x, lane = tid & 63, wave = tid >> 6;
    int i = blockIdx.x * SCAN_TILE + tid;
    int v = (i < N_NODES) ? cnt[i] : 0;
#pragma unroll
    for (int d = 1; d < 64; d <<= 1) v += __shfl_xor(v, d, 64);
    if (lane == 0) wsum[wave] = v;
    __syncthreads();
    if (wave == 0) {
        int s = (lane < 16) ? wsum[lane] : 0;
#pragma unroll
        for (int d = 1; d < 16; d <<= 1) s += __shfl_xor(s, d, 64);
        if (lane == 0) bsum[blockIdx.x] = s;
    }
}

__global__ __launch_bounds__(128) void scan_offsets(const int* __restrict__ bsum,
                                                    int* __restrict__ boff) {
    __shared__ int wtot[2];
    const int tid = threadIdx.x, lane = tid & 63, wave = tid >> 6;
    int v = (tid < NBLK) ? bsum[tid] : 0;
    int x = v;
#pragma unroll
    for (int d = 1; d < 64; d <<= 1) {
        int y = __shfl_up(x, d, 64);
        if (lane >= d) x += y;
    }
    if (lane == 63) wtot[wave] = x;
    __syncthreads();
    int excl = (x - v) + (wave == 1 ? wtot[0] : 0);
    if (tid < NBLK) boff[tid] = excl;
}

__global__ __launch_bounds__(SCAN_TILE) void scan_apply(const int* __restrict__ cnt,
                                                        const int* __restrict__ boff,
                                                        int* __restrict__ rowptr,
                                                        int* __restrict__ cur) {
    __shared__ int wsum[16];
    const int tid = threadIdx.x, lane = tid & 63, wave = tid >> 6;
    int i = blockIdx.x * SCAN_TILE + tid;
    int v = (i < N_NODES) ? cnt[i] : 0;
    int x = v;
#pragma unroll
    for (int d = 1; d < 64; d <<= 1) {
        int y = __shfl_up(x, d, 64);
        if (lane >= d) x += y;
    }
    if (lane == 63) wsum[wave] = x;
    __syncthreads();
    if (wave == 0) {
        int s = (lane < 16) ? wsum[lane] : 0;
#pragma unroll
        for (int d = 1; d < 16; d <<= 1) {
            int y = __shfl_up(s, d, 64);
            if (lane >= d) s += y;
        }
        if (lane < 16) wsum[lane] = s;  // inclusive wave sums
    }
    __syncthreads();
    int waveoff = (wave == 0) ? 0 : wsum[wave - 1];
    int excl = boff[blockIdx.x] + waveoff + (x - v);
    if (i < N_NODES) { rowptr[i] = excl; cur[i] = excl; }
    if (blockIdx.x == 0 && tid == 0) rowptr[N_NODES] = N_EDGES;
}

__global__ __launch_bounds__(256) void fill_kernel(const int* __restrict__ src,
                                                   const int* __restrict__ dst,
                                                   int* __restrict__ cur,
                                                   int* __restrict__ csr_src) {
    int e = blockIdx.x * 256 + threadIdx.x;
    if (e >= N_EDGES) return;
    int d = dst[e];
    int pos = atomicAdd(&cur[d], 1);  // int atomic: safe
    csr_src[pos] = src[e];
}

// mean[node][:] = (1/deg) * sum_{s in N(node)} h[s][:]; 0 if deg==0.
// One wave per node; 4 edges per step: quarter-wave q (16 lanes) reads edge i+q,
// each lane holds 4 dims as uint2 (8 B). Cross-quarter combine via shfl_xor.
__global__ __launch_bounds__(256) void agg_mean(const int* __restrict__ rowptr,
                                                const int* __restrict__ csr_src,
                                                const ushort* __restrict__ h,
                                                ushort* __restrict__ mean) {
    int node = blockIdx.x * 4 + (threadIdx.x >> 6);
    if (node >= N_NODES) return;
    const int lane = threadIdx.x & 63;
    const int q = lane >> 4;        // quarter-wave: which edge in the 4-batch
    const int g = lane & 15;        // dim group: dims 4g..4g+3
    int beg = rowptr[node], end = rowptr[node + 1];
    float a0 = 0.f, a1 = 0.f, a2 = 0.f, a3 = 0.f;
    for (int i = beg; i < end; i += 4) {
        int e = i + q;
        if (e < end) {
            int s = csr_src[e];
            uint2 w = *(const uint2*)&h[(size_t)s * HID + g * 4];
            a0 += bf2f((ushort)(w.x & 0xffff));
            a1 += bf2f((ushort)(w.x >> 16));
            a2 += bf2f((ushort)(w.y & 0xffff));
            a3 += bf2f((ushort)(w.y >> 16));
        }
    }
    // combine the 4 quarter-wave partial sums (same dims, different edges)
    a0 += __shfl_xor(a0, 16, 64); a0 += __shfl_xor(a0, 32, 64);
    a1 += __shfl_xor(a1, 16, 64); a1 += __shfl_xor(a1, 32, 64);
    a2 += __shfl_xor(a2, 16, 64); a2 += __shfl_xor(a2, 32, 64);
    a3 += __shfl_xor(a3, 16, 64); a3 += __shfl_xor(a3, 32, 64);
    if (lane < 16) {
        float inv = (end > beg) ? 1.0f / (float)(end - beg) : 0.f;
        uint2 o;
        o.x = (uint)f2bf(a0 * inv) | ((uint)f2bf(a1 * inv) << 16);
        o.y = (uint)f2bf(a2 * inv) | ((uint)f2bf(a3 * inv) << 16);
        *(uint2*)&mean[(size_t)node * HID + lane * 4] = o;
    }
}

// out = [HAS_MEAN: mean@Wl +] bl + hin@Wr, optional PReLU.
// MFMA 16x16x32 bf16: 64 rows/block, 4 waves.
template <bool HAS_MEAN, bool HAS_PRELU, bool OUT_F32>
__global__ __launch_bounds__(256) void gemm_mfma(const ushort* __restrict__ mean,
                                                 const ushort* __restrict__ hin,
                                                 const float* __restrict__ Wl,
                                                 const float* __restrict__ bl,
                                                 const float* __restrict__ Wr,
                                                 const float* __restrict__ alpha_p,
                                                 void* __restrict__ out_p, int n) {
    __shared__ __align__(16) ushort sA[HAS_MEAN ? 64 : 1][LDSS];
    __shared__ __align__(16) ushort sH[64][LDSS];
    __shared__ __align__(16) ushort sWl[HAS_MEAN ? 64 : 1][LDSS];  // Wl^T: [n][k]
    __shared__ __align__(16) ushort sWr[64][LDSS];                 // Wr^T: [n][k]

    const int tid = threadIdx.x;
    const int row0 = blockIdx.x * 64;

    for (int idx = tid; idx < HID * HID; idx += 256) {
        int k = idx >> 6, nn = idx & 63;
        if (HAS_MEAN) sWl[nn][k] = f2bf(Wl[idx]);
        sWr[nn][k] = f2bf(Wr[idx]);
    }
    for (int idx = tid; idx < 64 * HID; idx += 256) {
        int r = idx >> 6, d = idx & 63;
        int g = row0 + r;
        ushort hv = 0, av = 0;
        if (g < n) {
            hv = hin[(size_t)g * HID + d];
            if (HAS_MEAN) av = mean[(size_t)g * HID + d];
        }
        sH[r][d] = hv;
        if (HAS_MEAN) sA[r][d] = av;
    }
    __syncthreads();

    const int wave = tid >> 6;
    const int lane = tid & 63;
    const int quad = lane >> 4;
    const int lr = lane & 15;
    const int r0 = wave * 16;

    const float alpha = HAS_PRELU ? alpha_p[0] : 0.f;

    for (int nt = 0; nt < 4; ++nt) {
        f32x4 acc = {0.f, 0.f, 0.f, 0.f};
#pragma unroll
        for (int ks = 0; ks < 2; ++ks) {
            int k0 = ks * 32 + quad * 8;
            bf16x8 hf = *(const bf16x8*)&sH[r0 + lr][k0];
            bf16x8 wr = *(const bf16x8*)&sWr[nt * 16 + lr][k0];
            acc = __builtin_amdgcn_mfma_f32_16x16x32_bf16(hf, wr, acc, 0, 0, 0);
            if (HAS_MEAN) {
                bf16x8 af = *(const bf16x8*)&sA[r0 + lr][k0];
                bf16x8 wl = *(const bf16x8*)&sWl[nt * 16 + lr][k0];
                acc = __builtin_amdgcn_mfma_f32_16x16x32_bf16(af, wl, acc, 0, 0, 0);
            }
        }
        int col = nt * 16 + lr;
        float bias = bl[col];
#pragma unroll
        for (int r = 0; r < 4; ++r) {
            int row = r0 + quad * 4 + r;  // C/D: col=lane&15, row=(lane>>4)*4+reg [m89]
            int g = row0 + row;
            if (g < n) {
                float v = acc[r] + bias;
                if (HAS_PRELU) v = (v >= 0.f) ? v : alpha * v;
                if (OUT_F32)
                    ((float*)out_p)[(size_t)g * HID + col] = v;
                else
                    ((ushort*)out_p)[(size_t)g * HID + col] = f2bf(v);
            }
        }
    }
}

extern "C" void kernel_launch(void* const* d_in, const int* in_sizes, int n_in,
                              void* d_out, int out_size, void* d_ws, size_t ws_size,
                              hipStream_t stream) {
    const int*   x    = (const int*)d_in[0];
    const int*   src  = (const int*)d_in[1];
    const int*   dst  = src + N_EDGES;
    const float* emb  = (const float*)d_in[3];
    const float* Wl1  = (const float*)d_in[4];
    const float* bl1  = (const float*)d_in[5];
    const float* Wr1  = (const float*)d_in[6];
    const float* a1   = (const float*)d_in[7];
    const float* Wl2  = (const float*)d_in[8];
    const float* bl2  = (const float*)d_in[9];
    const float* Wr2  = (const float*)d_in[10];
    const float* a2   = (const float*)d_in[11];
    const float* Wout = (const float*)d_in[12];
    const float* bout = (const float*)d_in[13];

    char* ws = (char*)d_ws;
    int*    cnt     = (int*)ws;                      //        0 ..   400,000
    int*    rowptr  = (int*)(ws + 400000);           //  400,000 ..   804,032
    int*    cur     = (int*)(ws + 804032);           //  804,032 .. 1,204,032
    int*    bsum    = (int*)(ws + 1204032);          //  +512
    int*    boff    = (int*)(ws + 1204544);          //  +512
    int*    csr_src = (int*)(ws + 1205056);          //  +5,000,000
    ushort* h0      = (ushort*)(ws + 6205056);       // 12.8 MB
    ushort* h1      = (ushort*)(ws + 19005056);      // 12.8 MB
    ushort* meanb   = (ushort*)(ws + 31805056);      // 12.8 MB (end: 44.6 MB)
    ushort* h2      = h0;                            // h0 dead after layer-1 gemm

    const int gemm_blocks = (N_NODES + 63) / 64;     // 1563
    const int agg_blocks  = (N_NODES + 3) / 4;       // 25000

    zero_kernel<<<(100000 + 1023) / 1024, 256, 0, stream>>>((float4*)cnt, 100000 / 4);
    embed_gather<<<(N_NODES * 16 + 255) / 256, 256, 0, stream>>>(x, emb, h0);
    degree_kernel<<<(N_EDGES + 255) / 256, 256, 0, stream>>>(dst, cnt);
    scan_blocksum<<<NBLK, SCAN_TILE, 0, stream>>>(cnt, bsum);
    scan_offsets<<<1, 128, 0, stream>>>(bsum, boff);
    scan_apply<<<NBLK, SCAN_TILE, 0, stream>>>(cnt, boff, rowptr, cur);
    fill_kernel<<<(N_EDGES + 255) / 256, 256, 0, stream>>>(src, dst, cur, csr_src);

    // layer 1
    agg_mean<<<agg_blocks, 256, 0, stream>>>(rowptr, csr_src, h0, meanb);
    gemm_mfma<true, true, false><<<gemm_blocks, 256, 0, stream>>>(meanb, h0, Wl1, bl1, Wr1, a1, h1, N_NODES);

    // layer 2
    agg_mean<<<agg_blocks, 256, 0, stream>>>(rowptr, csr_src, h1, meanb);
    gemm_mfma<true, true, false><<<gemm_blocks, 256, 0, stream>>>(meanb, h1, Wl2, bl2, Wr2, a2, h2, N_NODES);

    // output projection: float32 output
    gemm_mfma<false, false, true><<<gemm_blocks, 256, 0, stream>>>(meanb, h2, Wout, bout, Wout, a1, d_out, N_NODES);
}

// Round 7
// 363.846 us; speedup vs baseline: 2.9636x; 1.1170x over previous
//
#include <hip/hip_runtime.h>
#include <hip/hip_bf16.h>

#define N_NODES 100000
#define N_EDGES 1250000
#define HID 64
#define LDSS 72   // LDS row stride in bf16 elems: 64 + 8 pad (144 B rows)
#define SCAN_TILE 1024
#define NBLK ((N_NODES + SCAN_TILE - 1) / SCAN_TILE)   // 98
#define NPART 8
#define PART_SZ (N_NODES / NPART)                       // 12500

typedef __bf16 bf16x8 __attribute__((ext_vector_type(8)));
typedef float  f32x4  __attribute__((ext_vector_type(4)));

__device__ __forceinline__ float bf2f(ushort u) {
    union { unsigned int i; float f; } v; v.i = ((unsigned int)u) << 16; return v.f;
}
__device__ __forceinline__ ushort f2bf(float f) {
    union { float f; unsigned int i; } v; v.f = f;
    unsigned int x = v.i;
    return (ushort)((x + 0x7fffu + ((x >> 16) & 1u)) >> 16);  // RNE
}

// h0[i][:] = bf16(emb[x[i]][:])  — emb f32, h0 bf16. 4 f32 per thread.
__global__ __launch_bounds__(256) void embed_gather(const int* __restrict__ x,
                                                    const float* __restrict__ emb,
                                                    ushort* __restrict__ h0) {
    int t = blockIdx.x * 256 + threadIdx.x;
    if (t >= N_NODES * 16) return;
    int row = t >> 4, c = t & 15;
    int idx = x[row];
    float4 v = ((const float4*)(emb + (size_t)idx * HID))[c];
    ushort4 w;
    w.x = f2bf(v.x); w.y = f2bf(v.y); w.z = f2bf(v.z); w.w = f2bf(v.w);
    ((ushort4*)(h0 + (size_t)row * HID))[c] = w;
}

__global__ __launch_bounds__(256) void degree_kernel(const int* __restrict__ dst,
                                                     int* __restrict__ cnt) {
    int e = blockIdx.x * 256 + threadIdx.x;
    if (e < N_EDGES) atomicAdd(&cnt[dst[e]], 1);  // int atomic: always safe
}

// ---- parallel scan: 3 kernels, no cross-block deps ----
__global__ __launch_bounds__(SCAN_TILE) void scan_blocksum(const int* __restrict__ cnt,
                                                           int* __restrict__ bsum) {
    __shared__ int wsum[16];
    const int tid = threadIdx.x, lane = tid & 63, wave = tid >> 6;
    int i = blockIdx.x * SCAN_TILE + tid;
    int v = (i < N_NODES) ? cnt[i] : 0;
#pragma unroll
    for (int d = 1; d < 64; d <<= 1) v += __shfl_xor(v, d, 64);
    if (lane == 0) wsum[wave] = v;
    __syncthreads();
    if (wave == 0) {
        int s = (lane < 16) ? wsum[lane] : 0;
#pragma unroll
        for (int d = 1; d < 16; d <<= 1) s += __shfl_xor(s, d, 64);
        if (lane == 0) bsum[blockIdx.x] = s;
    }
}

__global__ __launch_bounds__(128) void scan_offsets(const int* __restrict__ bsum,
                                                    int* __restrict__ boff) {
    __shared__ int wtot[2];
    const int tid = threadIdx.x, lane = tid & 63, wave = tid >> 6;
    int v = (tid < NBLK) ? bsum[tid] : 0;
    int x = v;
#pragma unroll
    for (int d = 1; d < 64; d <<= 1) {
        int y = __shfl_up(x, d, 64);
        if (lane >= d) x += y;
    }
    if (lane == 63) wtot[wave] = x;
    __syncthreads();
    int excl = (x - v) + (wave == 1 ? wtot[0] : 0);
    if (tid < NBLK) boff[tid] = excl;
}

__global__ __launch_bounds__(SCAN_TILE) void scan_apply(const int* __restrict__ cnt,
                                                        const int* __restrict__ boff,
                                                        int* __restrict__ rowptr,
                                                        int* __restrict__ cur) {
    __shared__ int wsum[16];
    const int tid = threadIdx.x, lane = tid & 63, wave = tid >> 6;
    int i = blockIdx.x * SCAN_TILE + tid;
    int v = (i < N_NODES) ? cnt[i] : 0;
    int x = v;
#pragma unroll
    for (int d = 1; d < 64; d <<= 1) {
        int y = __shfl_up(x, d, 64);
        if (lane >= d) x += y;
    }
    if (lane == 63) wsum[wave] = x;
    __syncthreads();
    if (wave == 0) {
        int s = (lane < 16) ? wsum[lane] : 0;
#pragma unroll
        for (int d = 1; d < 16; d <<= 1) {
            int y = __shfl_up(s, d, 64);
            if (lane >= d) s += y;
        }
        if (lane < 16) wsum[lane] = s;  // inclusive wave sums
    }
    __syncthreads();
    int waveoff = (wave == 0) ? 0 : wsum[wave - 1];
    int excl = boff[blockIdx.x] + waveoff + (x - v);
    if (i < N_NODES) { rowptr[i] = excl; cur[i] = excl; }
    if (blockIdx.x == 0 && tid == 0) rowptr[N_NODES] = N_EDGES;
}

// XCD-partitioned CSR fill: block b handles dst-partition (b&7) over edge chunk (b>>3).
// All csr_src lines of one partition are written from one XCD -> full-line L2
// accumulation, single writeback (fixes the 17x write amplification seen in r6).
__global__ __launch_bounds__(256) void fill_kernel(const int* __restrict__ src,
                                                   const int* __restrict__ dst,
                                                   int* __restrict__ cur,
                                                   int* __restrict__ csr_src) {
    int p = blockIdx.x & (NPART - 1);
    int e = (blockIdx.x >> 3) * 256 + threadIdx.x;
    if (e >= N_EDGES) return;
    int d = dst[e];
    if (d >= p * PART_SZ && d < (p + 1) * PART_SZ) {
        int pos = atomicAdd(&cur[d], 1);
        csr_src[pos] = src[e];
    }
}

// mean[node][:] = (1/deg) * sum_{s in N(node)} h[s][:]; 0 if deg==0.
// One wave per node; 8 edges in flight: octet q (8 lanes) reads edge i+q,
// each lane holds 8 dims as uint4 (16 B). Cross-octet combine via shfl_xor.
__global__ __launch_bounds__(256) void agg_mean(const int* __restrict__ rowptr,
                                                const int* __restrict__ csr_src,
                                                const ushort* __restrict__ h,
                                                ushort* __restrict__ mean) {
    int node = blockIdx.x * 4 + (threadIdx.x >> 6);
    if (node >= N_NODES) return;
    const int lane = threadIdx.x & 63;
    const int q = lane >> 3;        // edge slot 0..7
    const int g = lane & 7;         // dim group: dims 8g..8g+7
    int beg = rowptr[node], end = rowptr[node + 1];
    float a[8] = {};
    for (int i = beg; i < end; i += 8) {
        int e = i + q;
        if (e < end) {
            int s = csr_src[e];
            uint4 w = *(const uint4*)&h[(size_t)s * HID + g * 8];
            a[0] += bf2f((ushort)(w.x & 0xffff)); a[1] += bf2f((ushort)(w.x >> 16));
            a[2] += bf2f((ushort)(w.y & 0xffff)); a[3] += bf2f((ushort)(w.y >> 16));
            a[4] += bf2f((ushort)(w.z & 0xffff)); a[5] += bf2f((ushort)(w.z >> 16));
            a[6] += bf2f((ushort)(w.w & 0xffff)); a[7] += bf2f((ushort)(w.w >> 16));
        }
    }
#pragma unroll
    for (int j = 0; j < 8; ++j) {
        a[j] += __shfl_xor(a[j], 8, 64);
        a[j] += __shfl_xor(a[j], 16, 64);
        a[j] += __shfl_xor(a[j], 32, 64);
    }
    if (lane < 8) {
        float inv = (end > beg) ? 1.0f / (float)(end - beg) : 0.f;
        uint4 o;
        o.x = (uint)f2bf(a[0] * inv) | ((uint)f2bf(a[1] * inv) << 16);
        o.y = (uint)f2bf(a[2] * inv) | ((uint)f2bf(a[3] * inv) << 16);
        o.z = (uint)f2bf(a[4] * inv) | ((uint)f2bf(a[5] * inv) << 16);
        o.w = (uint)f2bf(a[6] * inv) | ((uint)f2bf(a[7] * inv) << 16);
        *(uint4*)&mean[(size_t)node * HID + lane * 8] = o;
    }
}

// out = [HAS_MEAN: mean@Wl +] bl + hin@Wr, optional PReLU.
// MFMA 16x16x32 bf16: 64 rows/block, 4 waves.
template <bool HAS_MEAN, bool HAS_PRELU, bool OUT_F32>
__global__ __launch_bounds__(256) void gemm_mfma(const ushort* __restrict__ mean,
                                                 const ushort* __restrict__ hin,
                                                 const float* __restrict__ Wl,
                                                 const float* __restrict__ bl,
                                                 const float* __restrict__ Wr,
                                                 const float* __restrict__ alpha_p,
                                                 void* __restrict__ out_p, int n) {
    __shared__ __align__(16) ushort sA[HAS_MEAN ? 64 : 1][LDSS];
    __shared__ __align__(16) ushort sH[64][LDSS];
    __shared__ __align__(16) ushort sWl[HAS_MEAN ? 64 : 1][LDSS];  // Wl^T: [n][k]
    __shared__ __align__(16) ushort sWr[64][LDSS];                 // Wr^T: [n][k]

    const int tid = threadIdx.x;
    const int row0 = blockIdx.x * 64;

    for (int idx = tid; idx < HID * HID; idx += 256) {
        int k = idx >> 6, nn = idx & 63;
        if (HAS_MEAN) sWl[nn][k] = f2bf(Wl[idx]);
        sWr[nn][k] = f2bf(Wr[idx]);
    }
    for (int idx = tid; idx < 64 * HID; idx += 256) {
        int r = idx >> 6, d = idx & 63;
        int g = row0 + r;
        ushort hv = 0, av = 0;
        if (g < n) {
            hv = hin[(size_t)g * HID + d];
            if (HAS_MEAN) av = mean[(size_t)g * HID + d];
        }
        sH[r][d] = hv;
        if (HAS_MEAN) sA[r][d] = av;
    }
    __syncthreads();

    const int wave = tid >> 6;
    const int lane = tid & 63;
    const int quad = lane >> 4;
    const int lr = lane & 15;
    const int r0 = wave * 16;

    const float alpha = HAS_PRELU ? alpha_p[0] : 0.f;

    for (int nt = 0; nt < 4; ++nt) {
        f32x4 acc = {0.f, 0.f, 0.f, 0.f};
#pragma unroll
        for (int ks = 0; ks < 2; ++ks) {
            int k0 = ks * 32 + quad * 8;
            bf16x8 hf = *(const bf16x8*)&sH[r0 + lr][k0];
            bf16x8 wr = *(const bf16x8*)&sWr[nt * 16 + lr][k0];
            acc = __builtin_amdgcn_mfma_f32_16x16x32_bf16(hf, wr, acc, 0, 0, 0);
            if (HAS_MEAN) {
                bf16x8 af = *(const bf16x8*)&sA[r0 + lr][k0];
                bf16x8 wl = *(const bf16x8*)&sWl[nt * 16 + lr][k0];
                acc = __builtin_amdgcn_mfma_f32_16x16x32_bf16(af, wl, acc, 0, 0, 0);
            }
        }
        int col = nt * 16 + lr;
        float bias = bl[col];
#pragma unroll
        for (int r = 0; r < 4; ++r) {
            int row = r0 + quad * 4 + r;  // C/D: col=lane&15, row=(lane>>4)*4+reg [m89]
            int g = row0 + row;
            if (g < n) {
                float v = acc[r] + bias;
                if (HAS_PRELU) v = (v >= 0.f) ? v : alpha * v;
                if (OUT_F32)
                    ((float*)out_p)[(size_t)g * HID + col] = v;
                else
                    ((ushort*)out_p)[(size_t)g * HID + col] = f2bf(v);
            }
        }
    }
}

extern "C" void kernel_launch(void* const* d_in, const int* in_sizes, int n_in,
                              void* d_out, int out_size, void* d_ws, size_t ws_size,
                              hipStream_t stream) {
    const int*   x    = (const int*)d_in[0];
    const int*   src  = (const int*)d_in[1];
    const int*   dst  = src + N_EDGES;
    const float* emb  = (const float*)d_in[3];
    const float* Wl1  = (const float*)d_in[4];
    const float* bl1  = (const float*)d_in[5];
    const float* Wr1  = (const float*)d_in[6];
    const float* a1   = (const float*)d_in[7];
    const float* Wl2  = (const float*)d_in[8];
    const float* bl2  = (const float*)d_in[9];
    const float* Wr2  = (const float*)d_in[10];
    const float* a2   = (const float*)d_in[11];
    const float* Wout = (const float*)d_in[12];
    const float* bout = (const float*)d_in[13];

    char* ws = (char*)d_ws;
    int*    cnt     = (int*)ws;                      //        0 ..   400,000
    int*    rowptr  = (int*)(ws + 400000);           //  400,000 ..   804,032
    int*    cur     = (int*)(ws + 804032);           //  804,032 .. 1,204,032
    int*    bsum    = (int*)(ws + 1204032);          //  +512
    int*    boff    = (int*)(ws + 1204544);          //  +512
    int*    csr_src = (int*)(ws + 1205056);          //  +5,000,000
    ushort* h0      = (ushort*)(ws + 6205056);       // 12.8 MB
    ushort* h1      = (ushort*)(ws + 19005056);      // 12.8 MB
    ushort* meanb   = (ushort*)(ws + 31805056);      // 12.8 MB (end: 44.6 MB)
    ushort* h2      = h0;                            // h0 dead after layer-1 gemm

    const int gemm_blocks = (N_NODES + 63) / 64;     // 1563
    const int agg_blocks  = (N_NODES + 3) / 4;       // 25000
    const int fill_blocks = NPART * ((N_EDGES + 255) / 256);  // 8 * 4883

    hipMemsetAsync(cnt, 0, N_NODES * sizeof(int), stream);
    embed_gather<<<(N_NODES * 16 + 255) / 256, 256, 0, stream>>>(x, emb, h0);
    degree_kernel<<<(N_EDGES + 255) / 256, 256, 0, stream>>>(dst, cnt);
    scan_blocksum<<<NBLK, SCAN_TILE, 0, stream>>>(cnt, bsum);
    scan_offsets<<<1, 128, 0, stream>>>(bsum, boff);
    scan_apply<<<NBLK, SCAN_TILE, 0, stream>>>(cnt, boff, rowptr, cur);
    fill_kernel<<<fill_blocks, 256, 0, stream>>>(src, dst, cur, csr_src);

    // layer 1
    agg_mean<<<agg_blocks, 256, 0, stream>>>(rowptr, csr_src, h0, meanb);
    gemm_mfma<true, true, false><<<gemm_blocks, 256, 0, stream>>>(meanb, h0, Wl1, bl1, Wr1, a1, h1, N_NODES);

    // layer 2
    agg_mean<<<agg_blocks, 256, 0, stream>>>(rowptr, csr_src, h1, meanb);
    gemm_mfma<true, true, false><<<gemm_blocks, 256, 0, stream>>>(meanb, h1, Wl2, bl2, Wr2, a2, h2, N_NODES);

    // output projection: float32 output
    gemm_mfma<false, false, true><<<gemm_blocks, 256, 0, stream>>>(meanb, h2, Wout, bout, Wout, a1, d_out, N_NODES);
}

// Round 8
// 350.070 us; speedup vs baseline: 3.0803x; 1.0394x over previous
//
#include <hip/hip_runtime.h>
#include <hip/hip_bf16.h>

#define N_NODES 100000
#define N_EDGES 1250000
#define HID 64
#define LDSS 72   // LDS row stride in bf16 elems: 64 + 8 pad (144 B rows)
#define SCAN_TILE 1024
#define NBLK ((N_NODES + SCAN_TILE - 1) / SCAN_TILE)   // 98

typedef __bf16 bf16x8 __attribute__((ext_vector_type(8)));
typedef float  f32x4  __attribute__((ext_vector_type(4)));

__device__ __forceinline__ float bf2f(ushort u) {
    union { unsigned int i; float f; } v; v.i = ((unsigned int)u) << 16; return v.f;
}
__device__ __forceinline__ ushort f2bf(float f) {
    union { float f; unsigned int i; } v; v.f = f;
    unsigned int x = v.i;
    return (ushort)((x + 0x7fffu + ((x >> 16) & 1u)) >> 16);  // RNE
}

// h0[i][:] = bf16(emb[x[i]][:])  — emb f32, h0 bf16. 4 f32 per thread.
__global__ __launch_bounds__(256) void embed_gather(const int* __restrict__ x,
                                                    const float* __restrict__ emb,
                                                    ushort* __restrict__ h0) {
    int t = blockIdx.x * 256 + threadIdx.x;
    if (t >= N_NODES * 16) return;
    int row = t >> 4, c = t & 15;
    int idx = x[row];
    float4 v = ((const float4*)(emb + (size_t)idx * HID))[c];
    ushort4 w;
    w.x = f2bf(v.x); w.y = f2bf(v.y); w.z = f2bf(v.z); w.w = f2bf(v.w);
    ((ushort4*)(h0 + (size_t)row * HID))[c] = w;
}

// Pass A: degree histogram AND per-edge stable rank in one atomic pass.
// Halves total global-atomic count vs separate degree+fill-cursor passes
// (r6->r7 counters showed ~50MB EA write floor from atomics alone).
__global__ __launch_bounds__(256) void rank_kernel(const int* __restrict__ dst,
                                                   int* __restrict__ cnt,
                                                   int* __restrict__ rank) {
    int e = blockIdx.x * 256 + threadIdx.x;
    if (e < N_EDGES) rank[e] = atomicAdd(&cnt[dst[e]], 1);
}

// ---- parallel scan: 3 kernels, no cross-block deps ----
__global__ __launch_bounds__(SCAN_TILE) void scan_blocksum(const int* __restrict__ cnt,
                                                           int* __restrict__ bsum) {
    __shared__ int wsum[16];
    const int tid = threadIdx.x, lane = tid & 63, wave = tid >> 6;
    int i = blockIdx.x * SCAN_TILE + tid;
    int v = (i < N_NODES) ? cnt[i] : 0;
#pragma unroll
    for (int d = 1; d < 64; d <<= 1) v += __shfl_xor(v, d, 64);
    if (lane == 0) wsum[wave] = v;
    __syncthreads();
    if (wave == 0) {
        int s = (lane < 16) ? wsum[lane] : 0;
#pragma unroll
        for (int d = 1; d < 16; d <<= 1) s += __shfl_xor(s, d, 64);
        if (lane == 0) bsum[blockIdx.x] = s;
    }
}

__global__ __launch_bounds__(128) void scan_offsets(const int* __restrict__ bsum,
                                                    int* __restrict__ boff) {
    __shared__ int wtot[2];
    const int tid = threadIdx.x, lane = tid & 63, wave = tid >> 6;
    int v = (tid < NBLK) ? bsum[tid] : 0;
    int x = v;
#pragma unroll
    for (int d = 1; d < 64; d <<= 1) {
        int y = __shfl_up(x, d, 64);
        if (lane >= d) x += y;
    }
    if (lane == 63) wtot[wave] = x;
    __syncthreads();
    int excl = (x - v) + (wave == 1 ? wtot[0] : 0);
    if (tid < NBLK) boff[tid] = excl;
}

__global__ __launch_bounds__(SCAN_TILE) void scan_apply(const int* __restrict__ cnt,
                                                        const int* __restrict__ boff,
                                                        int* __restrict__ rowptr) {
    __shared__ int wsum[16];
    const int tid = threadIdx.x, lane = tid & 63, wave = tid >> 6;
    int i = blockIdx.x * SCAN_TILE + tid;
    int v = (i < N_NODES) ? cnt[i] : 0;
    int x = v;
#pragma unroll
    for (int d = 1; d < 64; d <<= 1) {
        int y = __shfl_up(x, d, 64);
        if (lane >= d) x += y;
    }
    if (lane == 63) wsum[wave] = x;
    __syncthreads();
    if (wave == 0) {
        int s = (lane < 16) ? wsum[lane] : 0;
#pragma unroll
        for (int d = 1; d < 16; d <<= 1) {
            int y = __shfl_up(s, d, 64);
            if (lane >= d) s += y;
        }
        if (lane < 16) wsum[lane] = s;  // inclusive wave sums
    }
    __syncthreads();
    int waveoff = (wave == 0) ? 0 : wsum[wave - 1];
    int excl = boff[blockIdx.x] + waveoff + (x - v);
    if (i < N_NODES) rowptr[i] = excl;
    if (blockIdx.x == 0 && tid == 0) rowptr[N_NODES] = N_EDGES;
}

// Pass B: atomic-free CSR fill via precomputed ranks. Coalesced reads, one
// scatter write per edge.
__global__ __launch_bounds__(256) void fill_kernel(const int* __restrict__ src,
                                                   const int* __restrict__ dst,
                                                   const int* __restrict__ rank,
                                                   const int* __restrict__ rowptr,
                                                   int* __restrict__ csr_src) {
    int e = blockIdx.x * 256 + threadIdx.x;
    if (e >= N_EDGES) return;
    int d = dst[e];
    csr_src[rowptr[d] + rank[e]] = src[e];
}

// mean[node][:] = (1/deg) * sum_{s in N(node)} h[s][:]; 0 if deg==0.
// One wave per node; 8 edges in flight: octet q (8 lanes) reads edge i+q,
// each lane holds 8 dims as uint4 (16 B). Cross-octet combine via shfl_xor.
__global__ __launch_bounds__(256) void agg_mean(const int* __restrict__ rowptr,
                                                const int* __restrict__ csr_src,
                                                const ushort* __restrict__ h,
                                                ushort* __restrict__ mean) {
    int node = blockIdx.x * 4 + (threadIdx.x >> 6);
    if (node >= N_NODES) return;
    const int lane = threadIdx.x & 63;
    const int q = lane >> 3;        // edge slot 0..7
    const int g = lane & 7;         // dim group: dims 8g..8g+7
    int beg = rowptr[node], end = rowptr[node + 1];
    float a[8] = {};
    for (int i = beg; i < end; i += 8) {
        int e = i + q;
        if (e < end) {
            int s = csr_src[e];
            uint4 w = *(const uint4*)&h[(size_t)s * HID + g * 8];
            a[0] += bf2f((ushort)(w.x & 0xffff)); a[1] += bf2f((ushort)(w.x >> 16));
            a[2] += bf2f((ushort)(w.y & 0xffff)); a[3] += bf2f((ushort)(w.y >> 16));
            a[4] += bf2f((ushort)(w.z & 0xffff)); a[5] += bf2f((ushort)(w.z >> 16));
            a[6] += bf2f((ushort)(w.w & 0xffff)); a[7] += bf2f((ushort)(w.w >> 16));
        }
    }
#pragma unroll
    for (int j = 0; j < 8; ++j) {
        a[j] += __shfl_xor(a[j], 8, 64);
        a[j] += __shfl_xor(a[j], 16, 64);
        a[j] += __shfl_xor(a[j], 32, 64);
    }
    if (lane < 8) {
        float inv = (end > beg) ? 1.0f / (float)(end - beg) : 0.f;
        uint4 o;
        o.x = (uint)f2bf(a[0] * inv) | ((uint)f2bf(a[1] * inv) << 16);
        o.y = (uint)f2bf(a[2] * inv) | ((uint)f2bf(a[3] * inv) << 16);
        o.z = (uint)f2bf(a[4] * inv) | ((uint)f2bf(a[5] * inv) << 16);
        o.w = (uint)f2bf(a[6] * inv) | ((uint)f2bf(a[7] * inv) << 16);
        *(uint4*)&mean[(size_t)node * HID + lane * 8] = o;
    }
}

// out = [HAS_MEAN: mean@Wl +] bl + hin@Wr, optional PReLU.
// MFMA 16x16x32 bf16: 64 rows/block, 4 waves.
template <bool HAS_MEAN, bool HAS_PRELU, bool OUT_F32>
__global__ __launch_bounds__(256) void gemm_mfma(const ushort* __restrict__ mean,
                                                 const ushort* __restrict__ hin,
                                                 const float* __restrict__ Wl,
                                                 const float* __restrict__ bl,
                                                 const float* __restrict__ Wr,
                                                 const float* __restrict__ alpha_p,
                                                 void* __restrict__ out_p, int n) {
    __shared__ __align__(16) ushort sA[HAS_MEAN ? 64 : 1][LDSS];
    __shared__ __align__(16) ushort sH[64][LDSS];
    __shared__ __align__(16) ushort sWl[HAS_MEAN ? 64 : 1][LDSS];  // Wl^T: [n][k]
    __shared__ __align__(16) ushort sWr[64][LDSS];                 // Wr^T: [n][k]

    const int tid = threadIdx.x;
    const int row0 = blockIdx.x * 64;

    for (int idx = tid; idx < HID * HID; idx += 256) {
        int k = idx >> 6, nn = idx & 63;
        if (HAS_MEAN) sWl[nn][k] = f2bf(Wl[idx]);
        sWr[nn][k] = f2bf(Wr[idx]);
    }
    for (int idx = tid; idx < 64 * HID; idx += 256) {
        int r = idx >> 6, d = idx & 63;
        int g = row0 + r;
        ushort hv = 0, av = 0;
        if (g < n) {
            hv = hin[(size_t)g * HID + d];
            if (HAS_MEAN) av = mean[(size_t)g * HID + d];
        }
        sH[r][d] = hv;
        if (HAS_MEAN) sA[r][d] = av;
    }
    __syncthreads();

    const int wave = tid >> 6;
    const int lane = tid & 63;
    const int quad = lane >> 4;
    const int lr = lane & 15;
    const int r0 = wave * 16;

    const float alpha = HAS_PRELU ? alpha_p[0] : 0.f;

    for (int nt = 0; nt < 4; ++nt) {
        f32x4 acc = {0.f, 0.f, 0.f, 0.f};
#pragma unroll
        for (int ks = 0; ks < 2; ++ks) {
            int k0 = ks * 32 + quad * 8;
            bf16x8 hf = *(const bf16x8*)&sH[r0 + lr][k0];
            bf16x8 wr = *(const bf16x8*)&sWr[nt * 16 + lr][k0];
            acc = __builtin_amdgcn_mfma_f32_16x16x32_bf16(hf, wr, acc, 0, 0, 0);
            if (HAS_MEAN) {
                bf16x8 af = *(const bf16x8*)&sA[r0 + lr][k0];
                bf16x8 wl = *(const bf16x8*)&sWl[nt * 16 + lr][k0];
                acc = __builtin_amdgcn_mfma_f32_16x16x32_bf16(af, wl, acc, 0, 0, 0);
            }
        }
        int col = nt * 16 + lr;
        float bias = bl[col];
#pragma unroll
        for (int r = 0; r < 4; ++r) {
            int row = r0 + quad * 4 + r;  // C/D: col=lane&15, row=(lane>>4)*4+reg [m89]
            int g = row0 + row;
            if (g < n) {
                float v = acc[r] + bias;
                if (HAS_PRELU) v = (v >= 0.f) ? v : alpha * v;
                if (OUT_F32)
                    ((float*)out_p)[(size_t)g * HID + col] = v;
                else
                    ((ushort*)out_p)[(size_t)g * HID + col] = f2bf(v);
            }
        }
    }
}

extern "C" void kernel_launch(void* const* d_in, const int* in_sizes, int n_in,
                              void* d_out, int out_size, void* d_ws, size_t ws_size,
                              hipStream_t stream) {
    const int*   x    = (const int*)d_in[0];
    const int*   src  = (const int*)d_in[1];
    const int*   dst  = src + N_EDGES;
    const float* emb  = (const float*)d_in[3];
    const float* Wl1  = (const float*)d_in[4];
    const float* bl1  = (const float*)d_in[5];
    const float* Wr1  = (const float*)d_in[6];
    const float* a1   = (const float*)d_in[7];
    const float* Wl2  = (const float*)d_in[8];
    const float* bl2  = (const float*)d_in[9];
    const float* Wr2  = (const float*)d_in[10];
    const float* a2   = (const float*)d_in[11];
    const float* Wout = (const float*)d_in[12];
    const float* bout = (const float*)d_in[13];

    char* ws = (char*)d_ws;
    int*    cnt     = (int*)ws;                      //        0 ..   400,000
    int*    rowptr  = (int*)(ws + 400000);           //  400,000 ..   804,032
    int*    bsum    = (int*)(ws + 804032);           //  +512
    int*    boff    = (int*)(ws + 804544);           //  +512
    int*    rank    = (int*)(ws + 805056);           //  +5,000,000
    int*    csr_src = (int*)(ws + 5805056);          //  +5,000,000
    ushort* h0      = (ushort*)(ws + 10805056);      // 12.8 MB
    ushort* h1      = (ushort*)(ws + 23605056);      // 12.8 MB
    ushort* meanb   = (ushort*)(ws + 36405056);      // 12.8 MB (end: 49.2 MB)
    ushort* h2      = h0;                            // h0 dead after layer-1 gemm

    const int gemm_blocks = (N_NODES + 63) / 64;     // 1563
    const int agg_blocks  = (N_NODES + 3) / 4;       // 25000
    const int edge_blocks = (N_EDGES + 255) / 256;   // 4883

    hipMemsetAsync(cnt, 0, N_NODES * sizeof(int), stream);
    embed_gather<<<(N_NODES * 16 + 255) / 256, 256, 0, stream>>>(x, emb, h0);
    rank_kernel<<<edge_blocks, 256, 0, stream>>>(dst, cnt, rank);
    scan_blocksum<<<NBLK, SCAN_TILE, 0, stream>>>(cnt, bsum);
    scan_offsets<<<1, 128, 0, stream>>>(bsum, boff);
    scan_apply<<<NBLK, SCAN_TILE, 0, stream>>>(cnt, boff, rowptr);
    fill_kernel<<<edge_blocks, 256, 0, stream>>>(src, dst, rank, rowptr, csr_src);

    // layer 1
    agg_mean<<<agg_blocks, 256, 0, stream>>>(rowptr, csr_src, h0, meanb);
    gemm_mfma<true, true, false><<<gemm_blocks, 256, 0, stream>>>(meanb, h0, Wl1, bl1, Wr1, a1, h1, N_NODES);

    // layer 2
    agg_mean<<<agg_blocks, 256, 0, stream>>>(rowptr, csr_src, h1, meanb);
    gemm_mfma<true, true, false><<<gemm_blocks, 256, 0, stream>>>(meanb, h1, Wl2, bl2, Wr2, a2, h2, N_NODES);

    // output projection: float32 output
    gemm_mfma<false, false, true><<<gemm_blocks, 256, 0, stream>>>(meanb, h2, Wout, bout, Wout, a1, d_out, N_NODES);
}

// Round 9
// 324.322 us; speedup vs baseline: 3.3248x; 1.0794x over previous
//
#include <hip/hip_runtime.h>
#include <hip/hip_bf16.h>

#define N_NODES 100000
#define N_EDGES 1250000
#define HID 64
#define LDSS 72     // LDS row stride in bf16 elems: 64 + 8 pad (144 B rows)
#define NB 196      // buckets of 512 node-ids: (100000+511)/512
#define NBLOCK 128  // edge-slice blocks for P1/P3 (per (block,bucket) ~50 edges)

typedef __bf16 bf16x8 __attribute__((ext_vector_type(8)));
typedef float  f32x4  __attribute__((ext_vector_type(4)));

__device__ __forceinline__ float bf2f(ushort u) {
    union { unsigned int i; float f; } v; v.i = ((unsigned int)u) << 16; return v.f;
}
__device__ __forceinline__ ushort f2bf(float f) {
    union { float f; unsigned int i; } v; v.f = f;
    unsigned int x = v.i;
    return (ushort)((x + 0x7fffu + ((x >> 16) & 1u)) >> 16);  // RNE
}

// h0[i][:] = bf16(emb[x[i]][:])  — emb f32, h0 bf16. 4 f32 per thread.
__global__ __launch_bounds__(256) void embed_gather(const int* __restrict__ x,
                                                    const float* __restrict__ emb,
                                                    ushort* __restrict__ h0) {
    int t = blockIdx.x * 256 + threadIdx.x;
    if (t >= N_NODES * 16) return;
    int row = t >> 4, c = t & 15;
    int idx = x[row];
    float4 v = ((const float4*)(emb + (size_t)idx * HID))[c];
    ushort4 w;
    w.x = f2bf(v.x); w.y = f2bf(v.y); w.z = f2bf(v.z); w.w = f2bf(v.w);
    ((ushort4*)(h0 + (size_t)row * HID))[c] = w;
}

// ---- atomic-free CSR build: bucket counting sort, all atomics in LDS ----

// P1: per-block bucket histogram over this block's grid-stride edge slice.
__global__ __launch_bounds__(256) void p1_hist(const int* __restrict__ dst,
                                               int* __restrict__ gh) {
    __shared__ int hist[NB];
    const int tid = threadIdx.x;
    for (int i = tid; i < NB; i += 256) hist[i] = 0;
    __syncthreads();
    for (int e = blockIdx.x * 256 + tid; e < N_EDGES; e += NBLOCK * 256)
        atomicAdd(&hist[dst[e] >> 9], 1);
    __syncthreads();
    for (int i = tid; i < NB; i += 256) gh[blockIdx.x * NB + i] = hist[i];
}

// P2: per-bucket exclusive scan down the block axis; gh[b][v] -> block offset,
// btot[v] = bucket total. One block (128 threads) per bucket.
__global__ __launch_bounds__(128) void p2_scan(int* __restrict__ gh,
                                               int* __restrict__ btot) {
    __shared__ int w0tot;
    const int v = blockIdx.x;
    const int t = threadIdx.x, lane = t & 63, wave = t >> 6;
    int val = gh[t * NB + v];
    int x = val;
#pragma unroll
    for (int d = 1; d < 64; d <<= 1) {
        int y = __shfl_up(x, d, 64);
        if (lane >= d) x += y;
    }
    if (wave == 0 && lane == 63) w0tot = x;
    __syncthreads();
    int excl = (x - val) + (wave == 1 ? w0tot : 0);
    gh[t * NB + v] = excl;
    if (wave == 1 && lane == 63) btot[v] = excl + val;
}

// P2b: exclusive scan of the NB bucket totals -> bstart[NB+1].
__global__ __launch_bounds__(256) void p2b_scan(const int* __restrict__ btot,
                                                int* __restrict__ bstart) {
    __shared__ int wsum[4];
    const int t = threadIdx.x, lane = t & 63, wave = t >> 6;
    int v = (t < NB) ? btot[t] : 0;
    int x = v;
#pragma unroll
    for (int d = 1; d < 64; d <<= 1) {
        int y = __shfl_up(x, d, 64);
        if (lane >= d) x += y;
    }
    if (lane == 63) wsum[wave] = x;
    __syncthreads();
    if (wave == 0) {
        int s = (lane < 4) ? wsum[lane] : 0;
#pragma unroll
        for (int d = 1; d < 4; d <<= 1) {
            int y = __shfl_up(s, d, 64);
            if (lane >= d) s += y;
        }
        if (lane < 4) wsum[lane] = s;
    }
    __syncthreads();
    int waveoff = (wave == 0) ? 0 : wsum[wave - 1];
    int excl = waveoff + (x - v);
    if (t < NB) bstart[t] = excl;
    if (t == 0) bstart[NB] = N_EDGES;
}

// P3: scatter edges into bucket-major ebuf. Same slice mapping as P1; position
// = bstart[v] + gh[b][v] + LDS running count. Pack (d_local<<17)|src (26 bits).
__global__ __launch_bounds__(256) void p3_scatter(const int* __restrict__ src,
                                                  const int* __restrict__ dst,
                                                  const int* __restrict__ gh,
                                                  const int* __restrict__ bstart,
                                                  uint* __restrict__ ebuf) {
    __shared__ int base[NB];
    __shared__ int run[NB];
    const int tid = threadIdx.x;
    for (int i = tid; i < NB; i += 256) {
        base[i] = bstart[i] + gh[blockIdx.x * NB + i];
        run[i] = 0;
    }
    __syncthreads();
    for (int e = blockIdx.x * 256 + tid; e < N_EDGES; e += NBLOCK * 256) {
        int d = dst[e];
        int v = d >> 9;
        int r = atomicAdd(&run[v], 1);
        ebuf[base[v] + r] = ((uint)(d & 511) << 17) | (uint)src[e];
    }
}

// P4: one block per bucket. LDS histogram+scan of <=512 local nodes; writes
// rowptr for its nodes and scatters src into its private contiguous csr region.
__global__ __launch_bounds__(256) void p4_csr(const uint* __restrict__ ebuf,
                                              const int* __restrict__ bstart,
                                              int* __restrict__ rowptr,
                                              int* __restrict__ csr_src) {
    __shared__ int hist[512], hoff[512], run[512];
    __shared__ int wsum[4];
    const int v = blockIdx.x;
    const int tid = threadIdx.x, lane = tid & 63, wave = tid >> 6;
    const int node0 = v << 9;
    const int nn = min(512, N_NODES - node0);
    const int beg = bstart[v], end = bstart[v + 1];

    for (int i = tid; i < 512; i += 256) { hist[i] = 0; run[i] = 0; }
    __syncthreads();
    for (int e = beg + tid; e < end; e += 256)
        atomicAdd(&hist[ebuf[e] >> 17], 1);
    __syncthreads();
    // exclusive scan of hist[512]: thread t owns elems 2t, 2t+1
    int h0 = hist[2 * tid], h1 = hist[2 * tid + 1];
    int s = h0 + h1;
    int x = s;
#pragma unroll
    for (int d = 1; d < 64; d <<= 1) {
        int y = __shfl_up(x, d, 64);
        if (lane >= d) x += y;
    }
    if (lane == 63) wsum[wave] = x;
    __syncthreads();
    if (wave == 0) {
        int s2 = (lane < 4) ? wsum[lane] : 0;
#pragma unroll
        for (int d = 1; d < 4; d <<= 1) {
            int y = __shfl_up(s2, d, 64);
            if (lane >= d) s2 += y;
        }
        if (lane < 4) wsum[lane] = s2;
    }
    __syncthreads();
    int waveoff = (wave == 0) ? 0 : wsum[wave - 1];
    int excl = waveoff + (x - s);
    hoff[2 * tid] = excl;
    hoff[2 * tid + 1] = excl + h0;
    __syncthreads();
    // rowptr for this bucket's nodes (bucket-major order == global node order)
    for (int j = tid; j < nn; j += 256) rowptr[node0 + j] = beg + hoff[j];
    if (v == NB - 1 && tid == 0) rowptr[N_NODES] = N_EDGES;
    // scatter into private contiguous region
    for (int e = beg + tid; e < end; e += 256) {
        uint p = ebuf[e];
        int dl = p >> 17;
        int r = atomicAdd(&run[dl], 1);
        csr_src[beg + hoff[dl] + r] = (int)(p & 0x1FFFFu);
    }
}

// mean[node][:] = (1/deg) * sum_{s in N(node)} h[s][:]; 0 if deg==0.
// One wave per node; 8 edges in flight: octet q (8 lanes) reads edge i+q,
// each lane holds 8 dims as uint4 (16 B). Cross-octet combine via shfl_xor.
__global__ __launch_bounds__(256) void agg_mean(const int* __restrict__ rowptr,
                                                const int* __restrict__ csr_src,
                                                const ushort* __restrict__ h,
                                                ushort* __restrict__ mean) {
    int node = blockIdx.x * 4 + (threadIdx.x >> 6);
    if (node >= N_NODES) return;
    const int lane = threadIdx.x & 63;
    const int q = lane >> 3;        // edge slot 0..7
    const int g = lane & 7;         // dim group: dims 8g..8g+7
    int beg = rowptr[node], end = rowptr[node + 1];
    float a[8] = {};
    for (int i = beg; i < end; i += 8) {
        int e = i + q;
        if (e < end) {
            int s = csr_src[e];
            uint4 w = *(const uint4*)&h[(size_t)s * HID + g * 8];
            a[0] += bf2f((ushort)(w.x & 0xffff)); a[1] += bf2f((ushort)(w.x >> 16));
            a[2] += bf2f((ushort)(w.y & 0xffff)); a[3] += bf2f((ushort)(w.y >> 16));
            a[4] += bf2f((ushort)(w.z & 0xffff)); a[5] += bf2f((ushort)(w.z >> 16));
            a[6] += bf2f((ushort)(w.w & 0xffff)); a[7] += bf2f((ushort)(w.w >> 16));
        }
    }
#pragma unroll
    for (int j = 0; j < 8; ++j) {
        a[j] += __shfl_xor(a[j], 8, 64);
        a[j] += __shfl_xor(a[j], 16, 64);
        a[j] += __shfl_xor(a[j], 32, 64);
    }
    if (lane < 8) {
        float inv = (end > beg) ? 1.0f / (float)(end - beg) : 0.f;
        uint4 o;
        o.x = (uint)f2bf(a[0] * inv) | ((uint)f2bf(a[1] * inv) << 16);
        o.y = (uint)f2bf(a[2] * inv) | ((uint)f2bf(a[3] * inv) << 16);
        o.z = (uint)f2bf(a[4] * inv) | ((uint)f2bf(a[5] * inv) << 16);
        o.w = (uint)f2bf(a[6] * inv) | ((uint)f2bf(a[7] * inv) << 16);
        *(uint4*)&mean[(size_t)node * HID + lane * 8] = o;
    }
}

// out = [HAS_MEAN: mean@Wl +] bl + hin@Wr, optional PReLU.
// MFMA 16x16x32 bf16: 64 rows/block, 4 waves.
template <bool HAS_MEAN, bool HAS_PRELU, bool OUT_F32>
__global__ __launch_bounds__(256) void gemm_mfma(const ushort* __restrict__ mean,
                                                 const ushort* __restrict__ hin,
                                                 const float* __restrict__ Wl,
                                                 const float* __restrict__ bl,
                                                 const float* __restrict__ Wr,
                                                 const float* __restrict__ alpha_p,
                                                 void* __restrict__ out_p, int n) {
    __shared__ __align__(16) ushort sA[HAS_MEAN ? 64 : 1][LDSS];
    __shared__ __align__(16) ushort sH[64][LDSS];
    __shared__ __align__(16) ushort sWl[HAS_MEAN ? 64 : 1][LDSS];  // Wl^T: [n][k]
    __shared__ __align__(16) ushort sWr[64][LDSS];                 // Wr^T: [n][k]

    const int tid = threadIdx.x;
    const int row0 = blockIdx.x * 64;

    for (int idx = tid; idx < HID * HID; idx += 256) {
        int k = idx >> 6, nn = idx & 63;
        if (HAS_MEAN) sWl[nn][k] = f2bf(Wl[idx]);
        sWr[nn][k] = f2bf(Wr[idx]);
    }
    for (int idx = tid; idx < 64 * HID; idx += 256) {
        int r = idx >> 6, d = idx & 63;
        int g = row0 + r;
        ushort hv = 0, av = 0;
        if (g < n) {
            hv = hin[(size_t)g * HID + d];
            if (HAS_MEAN) av = mean[(size_t)g * HID + d];
        }
        sH[r][d] = hv;
        if (HAS_MEAN) sA[r][d] = av;
    }
    __syncthreads();

    const int wave = tid >> 6;
    const int lane = tid & 63;
    const int quad = lane >> 4;
    const int lr = lane & 15;
    const int r0 = wave * 16;

    const float alpha = HAS_PRELU ? alpha_p[0] : 0.f;

    for (int nt = 0; nt < 4; ++nt) {
        f32x4 acc = {0.f, 0.f, 0.f, 0.f};
#pragma unroll
        for (int ks = 0; ks < 2; ++ks) {
            int k0 = ks * 32 + quad * 8;
            bf16x8 hf = *(const bf16x8*)&sH[r0 + lr][k0];
            bf16x8 wr = *(const bf16x8*)&sWr[nt * 16 + lr][k0];
            acc = __builtin_amdgcn_mfma_f32_16x16x32_bf16(hf, wr, acc, 0, 0, 0);
            if (HAS_MEAN) {
                bf16x8 af = *(const bf16x8*)&sA[r0 + lr][k0];
                bf16x8 wl = *(const bf16x8*)&sWl[nt * 16 + lr][k0];
                acc = __builtin_amdgcn_mfma_f32_16x16x32_bf16(af, wl, acc, 0, 0, 0);
            }
        }
        int col = nt * 16 + lr;
        float bias = bl[col];
#pragma unroll
        for (int r = 0; r < 4; ++r) {
            int row = r0 + quad * 4 + r;  // C/D: col=lane&15, row=(lane>>4)*4+reg [m89]
            int g = row0 + row;
            if (g < n) {
                float v = acc[r] + bias;
                if (HAS_PRELU) v = (v >= 0.f) ? v : alpha * v;
                if (OUT_F32)
                    ((float*)out_p)[(size_t)g * HID + col] = v;
                else
                    ((ushort*)out_p)[(size_t)g * HID + col] = f2bf(v);
            }
        }
    }
}

extern "C" void kernel_launch(void* const* d_in, const int* in_sizes, int n_in,
                              void* d_out, int out_size, void* d_ws, size_t ws_size,
                              hipStream_t stream) {
    const int*   x    = (const int*)d_in[0];
    const int*   src  = (const int*)d_in[1];
    const int*   dst  = src + N_EDGES;
    const float* emb  = (const float*)d_in[3];
    const float* Wl1  = (const float*)d_in[4];
    const float* bl1  = (const float*)d_in[5];
    const float* Wr1  = (const float*)d_in[6];
    const float* a1   = (const float*)d_in[7];
    const float* Wl2  = (const float*)d_in[8];
    const float* bl2  = (const float*)d_in[9];
    const float* Wr2  = (const float*)d_in[10];
    const float* a2   = (const float*)d_in[11];
    const float* Wout = (const float*)d_in[12];
    const float* bout = (const float*)d_in[13];

    char* ws = (char*)d_ws;
    int*    gh      = (int*)ws;                      // 128*196*4 = 100,352 (pad 100,416)
    int*    btot    = (int*)(ws + 100416);           // 784 (pad 832)
    int*    bstart  = (int*)(ws + 101248);           // 788 (pad 832)
    int*    rowptr  = (int*)(ws + 102080);           // 400,004 (pad 400,064)
    uint*   ebuf    = (uint*)(ws + 502144);          // 5,000,000
    int*    csr_src = (int*)(ws + 5502144);          // 5,000,000
    ushort* h0      = (ushort*)(ws + 10502144);      // 12.8 MB
    ushort* h1      = (ushort*)(ws + 23302144);      // 12.8 MB
    ushort* meanb   = (ushort*)(ws + 36102144);      // 12.8 MB (end: 48.9 MB)
    ushort* h2      = h0;                            // h0 dead after layer-1 gemm

    const int gemm_blocks = (N_NODES + 63) / 64;     // 1563
    const int agg_blocks  = (N_NODES + 3) / 4;       // 25000

    embed_gather<<<(N_NODES * 16 + 255) / 256, 256, 0, stream>>>(x, emb, h0);
    p1_hist<<<NBLOCK, 256, 0, stream>>>(dst, gh);
    p2_scan<<<NB, 128, 0, stream>>>(gh, btot);
    p2b_scan<<<1, 256, 0, stream>>>(btot, bstart);
    p3_scatter<<<NBLOCK, 256, 0, stream>>>(src, dst, gh, bstart, ebuf);
    p4_csr<<<NB, 256, 0, stream>>>(ebuf, bstart, rowptr, csr_src);

    // layer 1
    agg_mean<<<agg_blocks, 256, 0, stream>>>(rowptr, csr_src, h0, meanb);
    gemm_mfma<true, true, false><<<gemm_blocks, 256, 0, stream>>>(meanb, h0, Wl1, bl1, Wr1, a1, h1, N_NODES);

    // layer 2
    agg_mean<<<agg_blocks, 256, 0, stream>>>(rowptr, csr_src, h1, meanb);
    gemm_mfma<true, true, false><<<gemm_blocks, 256, 0, stream>>>(meanb, h1, Wl2, bl2, Wr2, a2, h2, N_NODES);

    // output projection: float32 output
    gemm_mfma<false, false, true><<<gemm_blocks, 256, 0, stream>>>(meanb, h2, Wout, bout, Wout, a1, d_out, N_NODES);
}